// Round 17
// baseline (163.695 us; speedup 1.0000x reference)
//
#include <hip/hip_runtime.h>

typedef float f32x4 __attribute__((ext_vector_type(4)));
typedef __bf16 bf16x8 __attribute__((ext_vector_type(8)));
typedef unsigned int u32;
typedef unsigned short u16;

#define MTOT 65536
#define BTOT 1024
#define DD 64
#define LOG2E 1.44269504088896340736f
#define MFMA __builtin_amdgcn_mfma_f32_16x16x32_bf16

#define NROWBLK ((MTOT + BTOT) * 24 / 256)   // 6240
#define NVTBLK  (MTOT / 64)                  // 1024
#define ESPACE  (DD * BTOT + BTOT)           // 66560
#define NSLICE  8

__device__ __forceinline__ u16 f2bf(float f) { return __builtin_bit_cast(u16, (__bf16)f); }
__device__ __forceinline__ u32 pk2(float a, float b) {
    return (u32)f2bf(a) | ((u32)f2bf(b) << 16);
}
__device__ __forceinline__ bf16x8 ldg8(const u16* p) { return *reinterpret_cast<const bf16x8*>(p); }
__device__ __forceinline__ float fexp2(float x) {
#if __has_builtin(__builtin_amdgcn_exp2f)
    return __builtin_amdgcn_exp2f(x);
#else
    return exp2f(x);
#endif
}
__device__ __forceinline__ void glds16(const void* g, void* l) {
    __builtin_amdgcn_global_load_lds((const __attribute__((address_space(1))) u32*)g,
                                     (__attribute__((address_space(3))) u32*)l, 16, 0, 0);
}

// ---------------- single-kernel compaction: count + scan + scatter (1 block, deterministic) ----------------
__global__ __launch_bounds__(1024)
void k_compact(const int* __restrict__ mask, const float* __restrict__ TS,
               int* __restrict__ idxc, float* __restrict__ biasc, int* __restrict__ MaPtr)
{
    __shared__ int sc[1024];
    const int t = threadIdx.x;
    const int base = t * 64;                  // thread owns 64 consecutive m (keeps idxc m-sorted)
    int cnt = 0;
#pragma unroll 8
    for (int i = 0; i < 64; ++i) cnt += (mask[base + i] != 0);
    sc[t] = cnt;
    __syncthreads();
    // Hillis-Steele inclusive scan over 1024 per-thread counts
    for (int off = 1; off < 1024; off <<= 1) {
        int x = (t >= off) ? sc[t - off] : 0;
        __syncthreads();
        sc[t] += x;
        __syncthreads();
    }
    int woff = sc[t] - cnt;                   // exclusive prefix
    if (t == 1023) *MaPtr = sc[1023];
    for (int i = 0; i < 64; ++i) {
        int m = base + i;
        if (mask[m]) {
            idxc[woff]  = m;
            biasc[woff] = 0.3f * __expf(-0.1f * (1000.0f - TS[m]));
            ++woff;
        }
    }
}

// ---------------- gather-precompute: Qc rows, compacted KC rows, compacted interleaved Vt ----------------
__global__ __launch_bounds__(256)
void prep_all(const float* __restrict__ q, const float* __restrict__ ctx,
              const float* __restrict__ K, const float* __restrict__ CT,
              const float* __restrict__ V,
              const int* __restrict__ MaPtr, const int* __restrict__ idxc,
              const float* __restrict__ biasc,
              u16* __restrict__ Qc, u16* __restrict__ KC, u16* __restrict__ Vt)
{
    __shared__ u16 L[64][68];
    const int blk = blockIdx.x, t = threadIdx.x;
    const int Ma = *MaPtr;
    const int Mpad = (Ma + 63) & ~63;

    if (blk < NROWBLK) {
        const int R = MTOT + BTOT;
        int gid = blk * 256 + t;                   // R*24 total, exact
        float4 v = {0.f, 0.f, 0.f, 0.f};
        u16* dst;
        if (gid < R * 16) {                        // feature cols 0..63
            int row = gid >> 4, qd = gid & 15;
            bool isQ = row >= MTOT;
            if (isQ) {
                int r2 = row - MTOT;
                v = *reinterpret_cast<const float4*>(q + (size_t)r2 * 64 + qd * 4);
                v.x *= LOG2E; v.y *= LOG2E; v.z *= LOG2E; v.w *= LOG2E;
                dst = Qc + (size_t)r2 * 96 + qd * 4;
            } else {
                if (row >= Ma) return;             // pad-row features: stale is bounded; skip write
                v = *reinterpret_cast<const float4*>(K + (size_t)idxc[row] * 64 + qd * 4);
                dst = KC + (size_t)row * 96 + qd * 4;
            }
        } else if (gid < R * 20) {                 // context cols 64..79
            int i = gid - R * 16;
            int row = i >> 2, qd = i & 3;
            bool isQ = row >= MTOT;
            if (isQ) {
                int r2 = row - MTOT;
                v = *reinterpret_cast<const float4*>(ctx + (size_t)r2 * 16 + qd * 4);
                const float s = 0.5f * LOG2E; v.x *= s; v.y *= s; v.z *= s; v.w *= s;
                dst = Qc + (size_t)r2 * 96 + 64 + qd * 4;
            } else {
                if (row >= Ma) return;
                v = *reinterpret_cast<const float4*>(CT + (size_t)idxc[row] * 16 + qd * 4);
                dst = KC + (size_t)row * 96 + 64 + qd * 4;
            }
        } else {                                   // bias col 80 + pad 81..95
            int i = gid - R * 20;
            int row = i >> 2, qd = i & 3;
            bool isQ = row >= MTOT;
            if (isQ) {
                int r2 = row - MTOT;
                if (qd == 0) v.x = LOG2E;
                dst = Qc + (size_t)r2 * 96 + 80 + qd * 4;
            } else {
                if (row >= Mpad) return;           // never read
                if (qd == 0) v.x = (row < Ma) ? biasc[row] : -1000.0f;   // pad rows -> exp2 == 0
                dst = KC + (size_t)row * 96 + 80 + qd * 4;
            }
        }
        ushort4 o = { f2bf(v.x), f2bf(v.y), f2bf(v.z), f2bf(v.w) };
        *reinterpret_cast<ushort4*>(dst) = o;
        return;
    }

    // ---- Vt part: gather + interleaved transpose; blocks >= Mpad never read -> skip ----
    const int m0 = (blk - NROWBLK) * 64;
    if (m0 >= Mpad) return;
#pragma unroll
    for (int p = 0; p < 4; ++p) {
        int fi = t + p * 256;              // float4 index 0..1023
        int mi = fi >> 4, di = (fi & 15) << 2;
        int r = m0 + mi;
        float4 v = {0.f, 0.f, 0.f, 0.f};   // pad cols zero-filled (P=0 path, avoid NaN)
        if (r < Ma)
            v = *reinterpret_cast<const float4*>(V + (size_t)idxc[r] * 64 + di);
        ushort4 o = { f2bf(v.x), f2bf(v.y), f2bf(v.z), f2bf(v.w) };
        *reinterpret_cast<ushort4*>(&L[mi][di]) = o;
    }
    __syncthreads();
    const int d = t >> 2, seg = t & 3;
    u32 pk[8];
#pragma unroll
    for (int pr = 0; pr < 8; ++pr) {
        int c0 = seg * 16 + pr * 2;
        int g32 = c0 >> 5;
        int i0 = c0 & 31, i1 = (c0 + 1) & 31;
        int mp0 = g32 * 32 + (i0 >> 1) + (i0 & 1) * 16;   // interleave
        int mp1 = g32 * 32 + (i1 >> 1) + (i1 & 1) * 16;
        pk[pr] = (u32)L[mp0][d] | ((u32)L[mp1][d] << 16);
    }
    uint4 A = {pk[0], pk[1], pk[2], pk[3]}, B4 = {pk[4], pk[5], pk[6], pk[7]};
    u16* dst = Vt + (size_t)d * MTOT + m0 + seg * 16;
    *reinterpret_cast<uint4*>(dst)     = A;
    *reinterpret_cast<uint4*>(dst + 8) = B4;
}

// ---------------- main: compacted m-range, 8 waves/block, 32 rows/wave ----------------
__global__ __launch_bounds__(512, 4)
void epmem_mfma(const u16* __restrict__ Qc, const u16* __restrict__ KCg,
                const u16* __restrict__ Vtg, const int* __restrict__ MaPtr,
                float* __restrict__ pl, float* __restrict__ pacc,
                int SPLIT, int NB)
{
    __shared__ __align__(16) u16 KCs[2][64 * 96];    // 24 KB
    __shared__ __align__(16) u16 Vts[2][64 * 64];    // 16 KB
    __shared__ __align__(16) u16 Pb[8][32][40];      // 20 KB

    const int tid = threadIdx.x;
    const int w = tid >> 6, lane = tid & 63;
    const int l15 = lane & 15, g = lane >> 4;

    const int bid = blockIdx.x;
    const int o = (bid & 7) * (NB >> 3) + (bid >> 3);     // XCD-bijective (NB % 8 == 0)
    const int rt = o & 3, ch = o >> 2;                    // 4 row-tiles of 256
    const int rbase = rt * 256 + w * 32;                  // wave owns 32 b-rows

    // Q fragments: 2 b-subtiles x 3 k-chunks (LOG2E pre-scaled)
    const u16* qp = Qc + (size_t)(rbase + l15) * 96 + g * 8;
    bf16x8 qf[2][3];
#pragma unroll
    for (int sb = 0; sb < 2; ++sb)
#pragma unroll
        for (int c = 0; c < 3; ++c)
            qf[sb][c] = ldg8(qp + sb * 16 * 96 + c * 32);

    // compacted m-range (wave-uniform)
    const int Ma = *MaPtr;
    const int Mpad = (Ma + 63) & ~63;
    const int mper = ((Mpad + SPLIT - 1) / SPLIT + 63) & ~63;
    const int m0 = ch * mper;
    const int m1 = (m0 + mper < Mpad) ? (m0 + mper) : Mpad;
    const int ntiles = (m1 > m0) ? ((m1 - m0) >> 6) : 0;

    // staging offsets (waves 0-3 only; inverse-swizzled global source, linear LDS dest)
    int kgo[3], vgo[2];
    if (w < 4) {
#pragma unroll
        for (int i = 0; i < 3; ++i) {
            int ol = w * 3072 + i * 1024 + lane * 16;
            int row = ol / 192;
            int c = (ol - row * 192) >> 4;                   // 0..11
            int u = (c < 8) ? (c ^ (row & 7)) : (8 + ((c & 3) ^ (row & 3)));
            kgo[i] = row * 192 + u * 16;
        }
#pragma unroll
        for (int i = 0; i < 2; ++i) {
            int ol = w * 2048 + i * 1024 + lane * 16;
            int row = ol >> 7, c = (ol >> 4) & 7;
            int u = c ^ (row & 7);
            vgo[i] = row * (MTOT * 2) + u * 16;
        }
    }

    // constant ones B-fragment (col 0 = 1.0)
    const u32 ow = (l15 == 0) ? 0x3F803F80u : 0u;
    const uint4 ou = {ow, ow, ow, ow};
    const bf16x8 onesf = __builtin_bit_cast(bf16x8, ou);

    f32x4 acc[2][4];
    f32x4 accl[2];
#pragma unroll
    for (int sb = 0; sb < 2; ++sb) {
        accl[sb] = (f32x4){0, 0, 0, 0};
#pragma unroll
        for (int d4 = 0; d4 < 4; ++d4) acc[sb][d4] = (f32x4){0, 0, 0, 0};
    }

    if (ntiles > 0 && w < 4) {
        const char* kb = (const char*)KCg + (size_t)m0 * 192;
        const char* vb = (const char*)Vtg + (size_t)m0 * 2;
#pragma unroll
        for (int i = 0; i < 3; ++i) glds16(kb + kgo[i], (char*)KCs[0] + w * 3072 + i * 1024);
#pragma unroll
        for (int i = 0; i < 2; ++i) glds16(vb + vgo[i], (char*)Vts[0] + w * 2048 + i * 1024);
    }
    __syncthreads();

    char* pbw = (char*)Pb[w];
    const int xr = l15 & 7;
    const int x3 = l15 & 3;

    int cur = 0;
    for (int t = 0; t < ntiles; ++t) {
        if (t + 1 < ntiles && w < 4) {
            int mt = m0 + ((t + 1) << 6);
            const char* kb = (const char*)KCg + (size_t)mt * 192;
            const char* vb = (const char*)Vtg + (size_t)mt * 2;
            int nb = cur ^ 1;
#pragma unroll
            for (int i = 0; i < 3; ++i) glds16(kb + kgo[i], (char*)KCs[nb] + w * 3072 + i * 1024);
#pragma unroll
            for (int i = 0; i < 2; ++i) glds16(vb + vgo[i], (char*)Vts[nb] + w * 2048 + i * 1024);
        }
        const char* kcb = (const char*)KCs[cur];
        const char* vtb = (const char*)Vts[cur];

#pragma unroll
        for (int j = 0; j < 2; ++j) {               // two 32-m steps per 64-m tile
            bf16x8 kf[2][3];
#pragma unroll
            for (int s = 0; s < 2; ++s) {
                int row = j * 32 + s * 16 + l15;
                kf[s][0] = *reinterpret_cast<const bf16x8*>(kcb + row * 192 + (((0 + g) ^ xr) << 4));
                kf[s][1] = *reinterpret_cast<const bf16x8*>(kcb + row * 192 + (((4 + g) ^ xr) << 4));
                kf[s][2] = *reinterpret_cast<const bf16x8*>(kcb + row * 192 + ((8 + (g ^ x3)) << 4));
            }
            bf16x8 vf[4];
#pragma unroll
            for (int d4 = 0; d4 < 4; ++d4) {
                int row = d4 * 16 + l15;
                vf[d4] = *reinterpret_cast<const bf16x8*>(vtb + row * 128 + (((j * 4 + g) ^ xr) << 4));
            }

            f32x4 S00 = {0,0,0,0}, S01 = {0,0,0,0}, S10 = {0,0,0,0}, S11 = {0,0,0,0};
            S00 = MFMA(qf[0][0], kf[0][0], S00,0,0,0); S00 = MFMA(qf[0][1], kf[0][1], S00,0,0,0); S00 = MFMA(qf[0][2], kf[0][2], S00,0,0,0);
            S01 = MFMA(qf[0][0], kf[1][0], S01,0,0,0); S01 = MFMA(qf[0][1], kf[1][1], S01,0,0,0); S01 = MFMA(qf[0][2], kf[1][2], S01,0,0,0);
            S10 = MFMA(qf[1][0], kf[0][0], S10,0,0,0); S10 = MFMA(qf[1][1], kf[0][1], S10,0,0,0); S10 = MFMA(qf[1][2], kf[0][2], S10,0,0,0);
            S11 = MFMA(qf[1][0], kf[1][0], S11,0,0,0); S11 = MFMA(qf[1][1], kf[1][1], S11,0,0,0); S11 = MFMA(qf[1][2], kf[1][2], S11,0,0,0);

#pragma unroll
            for (int r = 0; r < 4; ++r) {
                float p00 = fexp2(S00[r]), p01 = fexp2(S01[r]);
                float p10 = fexp2(S10[r]), p11 = fexp2(S11[r]);
                int row0 = g * 4 + r, row1 = 16 + g * 4 + r;
                int cw = (((l15 >> 2) ^ r) << 4) | ((l15 & 3) << 2);
                *(u32*)(pbw + row0 * 80 + cw) = pk2(p00, p01);   // pair (m'=l15, 16+l15)
                *(u32*)(pbw + row1 * 80 + cw) = pk2(p10, p11);
            }
            bf16x8 pa0 = *reinterpret_cast<const bf16x8*>(pbw + l15 * 80        + ((g ^ x3) << 4));
            bf16x8 pa1 = *reinterpret_cast<const bf16x8*>(pbw + (16 + l15) * 80 + ((g ^ x3) << 4));

            acc[0][0] = MFMA(pa0, vf[0], acc[0][0],0,0,0); acc[0][1] = MFMA(pa0, vf[1], acc[0][1],0,0,0);
            acc[0][2] = MFMA(pa0, vf[2], acc[0][2],0,0,0); acc[0][3] = MFMA(pa0, vf[3], acc[0][3],0,0,0);
            acc[1][0] = MFMA(pa1, vf[0], acc[1][0],0,0,0); acc[1][1] = MFMA(pa1, vf[1], acc[1][1],0,0,0);
            acc[1][2] = MFMA(pa1, vf[2], acc[1][2],0,0,0); acc[1][3] = MFMA(pa1, vf[3], acc[1][3],0,0,0);
            accl[0] = MFMA(pa0, onesf, accl[0],0,0,0);     // lsum of quantized P
            accl[1] = MFMA(pa1, onesf, accl[1],0,0,0);
        }
        __syncthreads();
        cur ^= 1;
    }

    // pl[ch][b]: lsum in col 0 of accl (lanes l15==0)
    if (l15 == 0) {
#pragma unroll
        for (int sb = 0; sb < 2; ++sb)
            *reinterpret_cast<f32x4*>(pl + (size_t)ch * BTOT + rbase + sb * 16 + g * 4) = accl[sb];
    }

    // pacc[ch][d][b]
    float* bp = pacc + ((size_t)ch * DD + l15) * BTOT + rbase + g * 4;
#pragma unroll
    for (int sb = 0; sb < 2; ++sb)
#pragma unroll
        for (int d4 = 0; d4 < 4; ++d4)
            *reinterpret_cast<f32x4*>(bp + (size_t)(d4 * 16) * BTOT + sb * 16) = acc[sb][d4];
}

// ---------------- combine stage A: slice-reduce chunks ----------------
__global__ __launch_bounds__(256)
void combineA(const float* __restrict__ pl, const float* __restrict__ pacc,
              float* __restrict__ part, int cper)
{
    int e = blockIdx.x * 256 + threadIdx.x;        // < ESPACE (66560)
    int s = blockIdx.y;
    int c0 = s * cper;
    float v0 = 0.f, v1 = 0.f;
    if (e < DD * BTOT) {
        const float* p = pacc + (size_t)c0 * (DD * BTOT) + e;
#pragma unroll 2
        for (int i = 0; i + 1 < cper; i += 2) {
            v0 += p[(size_t)i * (DD * BTOT)];
            v1 += p[(size_t)(i + 1) * (DD * BTOT)];
        }
        if (cper & 1) v0 += p[(size_t)(cper - 1) * (DD * BTOT)];
    } else {
        const float* p = pl + (size_t)c0 * BTOT + (e - DD * BTOT);
#pragma unroll 2
        for (int i = 0; i + 1 < cper; i += 2) {
            v0 += p[(size_t)i * BTOT];
            v1 += p[(size_t)(i + 1) * BTOT];
        }
        if (cper & 1) v0 += p[(size_t)(cper - 1) * BTOT];
    }
    part[(size_t)s * ESPACE + e] = v0 + v1;
}

// ---------------- combine stage B: sum 8 slices + divide ----------------
__global__ __launch_bounds__(256)
void combineB(const float* __restrict__ part, float* __restrict__ out)
{
    int t = blockIdx.x * 256 + threadIdx.x;        // < 65536
    int d = t >> 10, b = t & 1023;
    float v = 0.f, lssum = 0.f;
#pragma unroll
    for (int s = 0; s < NSLICE; ++s) {
        v     += part[(size_t)s * ESPACE + t];
        lssum += part[(size_t)s * ESPACE + DD * BTOT + b];
    }
    out[(size_t)b * DD + d] = v / lssum;
}

extern "C" void kernel_launch(void* const* d_in, const int* in_sizes, int n_in,
                              void* d_out, int out_size, void* d_ws, size_t ws_size,
                              hipStream_t stream)
{
    const float* q    = (const float*)d_in[0];
    const float* ctx  = (const float*)d_in[1];
    const float* K    = (const float*)d_in[2];
    const float* V    = (const float*)d_in[3];
    const float* CT   = (const float*)d_in[4];
    const float* TS   = (const float*)d_in[5];
    const int*   mask = (const int*)d_in[6];

    char* wsb = (char*)d_ws;
    u16* Qc = (u16*)(wsb);                                // 1024*96*2   = 196608
    u16* KC = (u16*)(wsb + 196608);                       // 65536*96*2  = 12582912
    u16* Vt = (u16*)(wsb + 196608 + 12582912);            // 64*65536*2  = 8388608
    size_t fixed = 196608 + 12582912 + 8388608;           // 21168128

    int*   MaPtr      = (int*)(wsb + fixed);
    int*   idxc       = (int*)(wsb + fixed + 12288);      // 65536*4
    float* biasc      = (float*)(wsb + fixed + 12288 + 262144);
    size_t scratch_end = fixed + 12288 + 524288;          // 21704704

    size_t chunk = (size_t)BTOT * (DD + 1) * sizeof(float);   // 266240
    size_t partB = (size_t)NSLICE * ESPACE * sizeof(float);   // 2129920
    int SPLIT = (int)((ws_size - scratch_end - partB) / chunk);
    if (SPLIT > 128) SPLIT = 128;                          // NB=512 = 2 blocks/CU
    SPLIT &= ~7;
    if (SPLIT < 8) SPLIT = 8;

    float* pl   = (float*)(wsb + scratch_end);            // [SPLIT][1024]
    float* pacc = pl + (size_t)SPLIT * BTOT;              // [SPLIT][64][1024]
    float* part = pacc + (size_t)SPLIT * DD * BTOT;       // [8][66560]

    int cper = SPLIT / NSLICE;

    k_compact<<<1, 1024, 0, stream>>>(mask, TS, idxc, biasc, MaPtr);

    prep_all<<<NROWBLK + NVTBLK, 256, 0, stream>>>(q, ctx, K, CT, V, MaPtr, idxc, biasc,
                                                   Qc, KC, Vt);

    int NB = 4 * SPLIT;                                    // 4 row-tiles of 256 rows
    epmem_mfma<<<NB, 512, 0, stream>>>(Qc, KC, Vt, MaPtr, pl, pacc, SPLIT, NB);

    dim3 gA((ESPACE + 255) / 256, NSLICE);
    combineA<<<gA, 256, 0, stream>>>(pl, pacc, part, cper);
    combineB<<<(DD * BTOT) / 256, 256, 0, stream>>>(part, (float*)d_out);
}

// Round 18
// 54.425 us; speedup vs baseline: 3.0077x; 3.0077x over previous
//
#include <hip/hip_runtime.h>

typedef float f32x4 __attribute__((ext_vector_type(4)));
typedef __bf16 bf16x8 __attribute__((ext_vector_type(8)));
typedef unsigned int u32;
typedef unsigned short u16;

#define MTOT 65536
#define BTOT 1024
#define DD 64
#define LOG2E 1.44269504088896340736f
#define MFMA __builtin_amdgcn_mfma_f32_16x16x32_bf16

#define NROWBLK ((MTOT + BTOT) * 24 / 256)   // 6240
#define NVTBLK  (MTOT / 64)                  // 1024
#define ESPACE  (DD * BTOT + BTOT)           // 66560
#define NSLICE  8

__device__ __forceinline__ u16 f2bf(float f) { return __builtin_bit_cast(u16, (__bf16)f); }
__device__ __forceinline__ u32 pk2(float a, float b) {
    return (u32)f2bf(a) | ((u32)f2bf(b) << 16);
}
__device__ __forceinline__ bf16x8 ldg8(const u16* p) { return *reinterpret_cast<const bf16x8*>(p); }
__device__ __forceinline__ float fexp2(float x) {
#if __has_builtin(__builtin_amdgcn_exp2f)
    return __builtin_amdgcn_exp2f(x);
#else
    return exp2f(x);
#endif
}
__device__ __forceinline__ void glds16(const void* g, void* l) {
    __builtin_amdgcn_global_load_lds((const __attribute__((address_space(1))) u32*)g,
                                     (__attribute__((address_space(3))) u32*)l, 16, 0, 0);
}

// ---------------- compaction: count -> parallel scan -> scatter (R16-proven) ----------------
__global__ __launch_bounds__(256)
void k_count(const int* __restrict__ mask, int* __restrict__ blockCount)
{
    int t = threadIdx.x;
    int m = blockIdx.x * 256 + t;
    int active = mask[m] != 0;
    unsigned long long bal = __ballot(active);
    __shared__ int wc[4];
    if ((t & 63) == 0) wc[t >> 6] = __popcll(bal);
    __syncthreads();
    if (t == 0) blockCount[blockIdx.x] = wc[0] + wc[1] + wc[2] + wc[3];
}

__global__ __launch_bounds__(256)
void k_scan(const int* __restrict__ blockCount, int* __restrict__ blockOff,
            int* __restrict__ MaPtr)
{
    __shared__ int sdata[256];
    int t = threadIdx.x;
    int v = blockCount[t];
    sdata[t] = v;
    __syncthreads();
#pragma unroll
    for (int off = 1; off < 256; off <<= 1) {
        int x = (t >= off) ? sdata[t - off] : 0;
        __syncthreads();
        sdata[t] += x;
        __syncthreads();
    }
    blockOff[t] = sdata[t] - v;            // exclusive prefix
    if (t == 255) *MaPtr = sdata[255];
}

__global__ __launch_bounds__(256)
void k_scatter(const int* __restrict__ mask, const float* __restrict__ TS,
               const int* __restrict__ blockOff,
               int* __restrict__ idxc, float* __restrict__ biasc)
{
    int t = threadIdx.x;
    int m = blockIdx.x * 256 + t;
    int active = mask[m] != 0;
    unsigned long long bal = __ballot(active);
    int lane = t & 63, wid = t >> 6;
    __shared__ int wc[4];
    if (lane == 0) wc[wid] = __popcll(bal);
    __syncthreads();
    int base = blockOff[blockIdx.x];
    for (int w = 0; w < wid; ++w) base += wc[w];
    int rank = __popcll(bal & ((1ull << lane) - 1ull));
    if (active) {
        int dst = base + rank;
        idxc[dst]  = m;
        biasc[dst] = 0.3f * __expf(-0.1f * (1000.0f - TS[m]));
    }
}

// ---------------- gather-precompute: Qc rows, compacted KC rows, compacted interleaved Vt ----------------
__global__ __launch_bounds__(256)
void prep_all(const float* __restrict__ q, const float* __restrict__ ctx,
              const float* __restrict__ K, const float* __restrict__ CT,
              const float* __restrict__ V,
              const int* __restrict__ MaPtr, const int* __restrict__ idxc,
              const float* __restrict__ biasc,
              u16* __restrict__ Qc, u16* __restrict__ KC, u16* __restrict__ Vt)
{
    __shared__ u16 L[64][68];
    const int blk = blockIdx.x, t = threadIdx.x;
    const int Ma = *MaPtr;
    const int Mpad = (Ma + 63) & ~63;

    if (blk < NROWBLK) {
        const int R = MTOT + BTOT;
        int gid = blk * 256 + t;                   // R*24 total, exact
        float4 v = {0.f, 0.f, 0.f, 0.f};
        u16* dst;
        if (gid < R * 16) {                        // feature cols 0..63
            int row = gid >> 4, qd = gid & 15;
            bool isQ = row >= MTOT;
            if (isQ) {
                int r2 = row - MTOT;
                v = *reinterpret_cast<const float4*>(q + (size_t)r2 * 64 + qd * 4);
                v.x *= LOG2E; v.y *= LOG2E; v.z *= LOG2E; v.w *= LOG2E;
                dst = Qc + (size_t)r2 * 96 + qd * 4;
            } else {
                if (row >= Ma) return;             // pad-row features: stale is bounded; skip
                v = *reinterpret_cast<const float4*>(K + (size_t)idxc[row] * 64 + qd * 4);
                dst = KC + (size_t)row * 96 + qd * 4;
            }
        } else if (gid < R * 20) {                 // context cols 64..79
            int i = gid - R * 16;
            int row = i >> 2, qd = i & 3;
            bool isQ = row >= MTOT;
            if (isQ) {
                int r2 = row - MTOT;
                v = *reinterpret_cast<const float4*>(ctx + (size_t)r2 * 16 + qd * 4);
                const float s = 0.5f * LOG2E; v.x *= s; v.y *= s; v.z *= s; v.w *= s;
                dst = Qc + (size_t)r2 * 96 + 64 + qd * 4;
            } else {
                if (row >= Ma) return;
                v = *reinterpret_cast<const float4*>(CT + (size_t)idxc[row] * 16 + qd * 4);
                dst = KC + (size_t)row * 96 + 64 + qd * 4;
            }
        } else {                                   // bias col 80 + pad 81..95
            int i = gid - R * 20;
            int row = i >> 2, qd = i & 3;
            bool isQ = row >= MTOT;
            if (isQ) {
                int r2 = row - MTOT;
                if (qd == 0) v.x = LOG2E;
                dst = Qc + (size_t)r2 * 96 + 80 + qd * 4;
            } else {
                if (row >= Mpad) return;           // never read
                if (qd == 0) v.x = (row < Ma) ? biasc[row] : -1000.0f;   // pad rows -> exp2 == 0
                dst = KC + (size_t)row * 96 + 80 + qd * 4;
            }
        }
        ushort4 o = { f2bf(v.x), f2bf(v.y), f2bf(v.z), f2bf(v.w) };
        *reinterpret_cast<ushort4*>(dst) = o;
        return;
    }

    // ---- Vt part: gather + interleaved transpose; blocks >= Mpad never read -> skip ----
    const int m0 = (blk - NROWBLK) * 64;
    if (m0 >= Mpad) return;
#pragma unroll
    for (int p = 0; p < 4; ++p) {
        int fi = t + p * 256;              // float4 index 0..1023
        int mi = fi >> 4, di = (fi & 15) << 2;
        int r = m0 + mi;
        float4 v = {0.f, 0.f, 0.f, 0.f};   // pad cols zero-filled (P=0 path, avoid NaN)
        if (r < Ma)
            v = *reinterpret_cast<const float4*>(V + (size_t)idxc[r] * 64 + di);
        ushort4 o = { f2bf(v.x), f2bf(v.y), f2bf(v.z), f2bf(v.w) };
        *reinterpret_cast<ushort4*>(&L[mi][di]) = o;
    }
    __syncthreads();
    const int d = t >> 2, seg = t & 3;
    u32 pk[8];
#pragma unroll
    for (int pr = 0; pr < 8; ++pr) {
        int c0 = seg * 16 + pr * 2;
        int g32 = c0 >> 5;
        int i0 = c0 & 31, i1 = (c0 + 1) & 31;
        int mp0 = g32 * 32 + (i0 >> 1) + (i0 & 1) * 16;   // interleave
        int mp1 = g32 * 32 + (i1 >> 1) + (i1 & 1) * 16;
        pk[pr] = (u32)L[mp0][d] | ((u32)L[mp1][d] << 16);
    }
    uint4 A = {pk[0], pk[1], pk[2], pk[3]}, B4 = {pk[4], pk[5], pk[6], pk[7]};
    u16* dst = Vt + (size_t)d * MTOT + m0 + seg * 16;
    *reinterpret_cast<uint4*>(dst)     = A;
    *reinterpret_cast<uint4*>(dst + 8) = B4;
}

// ---------------- main: compacted m-range, 8 waves/block, bf16 pacc ----------------
__global__ __launch_bounds__(512, 4)
void epmem_mfma(const u16* __restrict__ Qc, const u16* __restrict__ KCg,
                const u16* __restrict__ Vtg, const int* __restrict__ MaPtr,
                float* __restrict__ pl, u16* __restrict__ paccb,
                int SPLIT, int NB)
{
    __shared__ __align__(16) u16 KCs[2][64 * 96];    // 24 KB
    __shared__ __align__(16) u16 Vts[2][64 * 64];    // 16 KB
    __shared__ __align__(16) u16 Pb[8][32][40];      // 20 KB

    const int tid = threadIdx.x;
    const int w = tid >> 6, lane = tid & 63;
    const int l15 = lane & 15, g = lane >> 4;

    const int bid = blockIdx.x;
    const int o = (bid & 7) * (NB >> 3) + (bid >> 3);     // XCD-bijective (NB % 8 == 0)
    const int rt = o & 3, ch = o >> 2;                    // 4 row-tiles of 256
    const int rbase = rt * 256 + w * 32;                  // wave owns 32 b-rows

    const u16* qp = Qc + (size_t)(rbase + l15) * 96 + g * 8;
    bf16x8 qf[2][3];
#pragma unroll
    for (int sb = 0; sb < 2; ++sb)
#pragma unroll
        for (int c = 0; c < 3; ++c)
            qf[sb][c] = ldg8(qp + sb * 16 * 96 + c * 32);

    const int Ma = *MaPtr;
    const int Mpad = (Ma + 63) & ~63;
    const int mper = ((Mpad + SPLIT - 1) / SPLIT + 63) & ~63;
    const int m0 = ch * mper;
    const int m1 = (m0 + mper < Mpad) ? (m0 + mper) : Mpad;
    const int ntiles = (m1 > m0) ? ((m1 - m0) >> 6) : 0;

    int kgo[3], vgo[2];
    if (w < 4) {
#pragma unroll
        for (int i = 0; i < 3; ++i) {
            int ol = w * 3072 + i * 1024 + lane * 16;
            int row = ol / 192;
            int c = (ol - row * 192) >> 4;                   // 0..11
            int u = (c < 8) ? (c ^ (row & 7)) : (8 + ((c & 3) ^ (row & 3)));
            kgo[i] = row * 192 + u * 16;
        }
#pragma unroll
        for (int i = 0; i < 2; ++i) {
            int ol = w * 2048 + i * 1024 + lane * 16;
            int row = ol >> 7, c = (ol >> 4) & 7;
            int u = c ^ (row & 7);
            vgo[i] = row * (MTOT * 2) + u * 16;
        }
    }

    const u32 ow = (l15 == 0) ? 0x3F803F80u : 0u;
    const uint4 ou = {ow, ow, ow, ow};
    const bf16x8 onesf = __builtin_bit_cast(bf16x8, ou);

    f32x4 acc[2][4];
    f32x4 accl[2];
#pragma unroll
    for (int sb = 0; sb < 2; ++sb) {
        accl[sb] = (f32x4){0, 0, 0, 0};
#pragma unroll
        for (int d4 = 0; d4 < 4; ++d4) acc[sb][d4] = (f32x4){0, 0, 0, 0};
    }

    if (ntiles > 0 && w < 4) {
        const char* kb = (const char*)KCg + (size_t)m0 * 192;
        const char* vb = (const char*)Vtg + (size_t)m0 * 2;
#pragma unroll
        for (int i = 0; i < 3; ++i) glds16(kb + kgo[i], (char*)KCs[0] + w * 3072 + i * 1024);
#pragma unroll
        for (int i = 0; i < 2; ++i) glds16(vb + vgo[i], (char*)Vts[0] + w * 2048 + i * 1024);
    }
    __syncthreads();

    char* pbw = (char*)Pb[w];
    const int xr = l15 & 7;
    const int x3 = l15 & 3;

    int cur = 0;
    for (int t = 0; t < ntiles; ++t) {
        if (t + 1 < ntiles && w < 4) {
            int mt = m0 + ((t + 1) << 6);
            const char* kb = (const char*)KCg + (size_t)mt * 192;
            const char* vb = (const char*)Vtg + (size_t)mt * 2;
            int nb = cur ^ 1;
#pragma unroll
            for (int i = 0; i < 3; ++i) glds16(kb + kgo[i], (char*)KCs[nb] + w * 3072 + i * 1024);
#pragma unroll
            for (int i = 0; i < 2; ++i) glds16(vb + vgo[i], (char*)Vts[nb] + w * 2048 + i * 1024);
        }
        const char* kcb = (const char*)KCs[cur];
        const char* vtb = (const char*)Vts[cur];

#pragma unroll
        for (int j = 0; j < 2; ++j) {               // two 32-m steps per 64-m tile
            bf16x8 kf[2][3];
#pragma unroll
            for (int s = 0; s < 2; ++s) {
                int row = j * 32 + s * 16 + l15;
                kf[s][0] = *reinterpret_cast<const bf16x8*>(kcb + row * 192 + (((0 + g) ^ xr) << 4));
                kf[s][1] = *reinterpret_cast<const bf16x8*>(kcb + row * 192 + (((4 + g) ^ xr) << 4));
                kf[s][2] = *reinterpret_cast<const bf16x8*>(kcb + row * 192 + ((8 + (g ^ x3)) << 4));
            }
            bf16x8 vf[4];
#pragma unroll
            for (int d4 = 0; d4 < 4; ++d4) {
                int row = d4 * 16 + l15;
                vf[d4] = *reinterpret_cast<const bf16x8*>(vtb + row * 128 + (((j * 4 + g) ^ xr) << 4));
            }

            f32x4 S00 = {0,0,0,0}, S01 = {0,0,0,0}, S10 = {0,0,0,0}, S11 = {0,0,0,0};
            S00 = MFMA(qf[0][0], kf[0][0], S00,0,0,0); S00 = MFMA(qf[0][1], kf[0][1], S00,0,0,0); S00 = MFMA(qf[0][2], kf[0][2], S00,0,0,0);
            S01 = MFMA(qf[0][0], kf[1][0], S01,0,0,0); S01 = MFMA(qf[0][1], kf[1][1], S01,0,0,0); S01 = MFMA(qf[0][2], kf[1][2], S01,0,0,0);
            S10 = MFMA(qf[1][0], kf[0][0], S10,0,0,0); S10 = MFMA(qf[1][1], kf[0][1], S10,0,0,0); S10 = MFMA(qf[1][2], kf[0][2], S10,0,0,0);
            S11 = MFMA(qf[1][0], kf[1][0], S11,0,0,0); S11 = MFMA(qf[1][1], kf[1][1], S11,0,0,0); S11 = MFMA(qf[1][2], kf[1][2], S11,0,0,0);

#pragma unroll
            for (int r = 0; r < 4; ++r) {
                float p00 = fexp2(S00[r]), p01 = fexp2(S01[r]);
                float p10 = fexp2(S10[r]), p11 = fexp2(S11[r]);
                int row0 = g * 4 + r, row1 = 16 + g * 4 + r;
                int cw = (((l15 >> 2) ^ r) << 4) | ((l15 & 3) << 2);
                *(u32*)(pbw + row0 * 80 + cw) = pk2(p00, p01);   // pair (m'=l15, 16+l15)
                *(u32*)(pbw + row1 * 80 + cw) = pk2(p10, p11);
            }
            bf16x8 pa0 = *reinterpret_cast<const bf16x8*>(pbw + l15 * 80        + ((g ^ x3) << 4));
            bf16x8 pa1 = *reinterpret_cast<const bf16x8*>(pbw + (16 + l15) * 80 + ((g ^ x3) << 4));

            acc[0][0] = MFMA(pa0, vf[0], acc[0][0],0,0,0); acc[0][1] = MFMA(pa0, vf[1], acc[0][1],0,0,0);
            acc[0][2] = MFMA(pa0, vf[2], acc[0][2],0,0,0); acc[0][3] = MFMA(pa0, vf[3], acc[0][3],0,0,0);
            acc[1][0] = MFMA(pa1, vf[0], acc[1][0],0,0,0); acc[1][1] = MFMA(pa1, vf[1], acc[1][1],0,0,0);
            acc[1][2] = MFMA(pa1, vf[2], acc[1][2],0,0,0); acc[1][3] = MFMA(pa1, vf[3], acc[1][3],0,0,0);
            accl[0] = MFMA(pa0, onesf, accl[0],0,0,0);     // lsum of quantized P
            accl[1] = MFMA(pa1, onesf, accl[1],0,0,0);
        }
        __syncthreads();
        cur ^= 1;
    }

    // pl[ch][b] (f32): lsum in col 0 of accl (lanes l15==0)
    if (l15 == 0) {
#pragma unroll
        for (int sb = 0; sb < 2; ++sb)
            *reinterpret_cast<f32x4*>(pl + (size_t)ch * BTOT + rbase + sb * 16 + g * 4) = accl[sb];
    }

    // paccb[ch][d][b] (bf16, packed pairs along b)
#pragma unroll
    for (int sb = 0; sb < 2; ++sb)
#pragma unroll
        for (int d4 = 0; d4 < 4; ++d4) {
            uint2 wv;
            wv.x = pk2(acc[sb][d4][0], acc[sb][d4][1]);
            wv.y = pk2(acc[sb][d4][2], acc[sb][d4][3]);
            *reinterpret_cast<uint2*>(paccb + ((size_t)ch * DD + d4 * 16 + l15) * BTOT
                                      + rbase + sb * 16 + g * 4) = wv;
        }
}

// ---------------- combine stage A: slice-reduce chunks (bf16 pacc, f32 pl) ----------------
__global__ __launch_bounds__(256)
void combineA(const float* __restrict__ pl, const u32* __restrict__ paccb,
              float* __restrict__ part, int cper)
{
    int e2 = blockIdx.x * 256 + threadIdx.x;       // pair index < 32768, then pl 1024
    int s = blockIdx.y;
    int c0 = s * cper;
    if (e2 < (DD * BTOT / 2)) {                    // pacc pair (2 consecutive b)
        const u32* p = paccb + (size_t)c0 * (DD * BTOT / 2) + e2;
        float s0 = 0.f, s1 = 0.f;
        for (int i = 0; i < cper; ++i) {
            u32 v = p[(size_t)i * (DD * BTOT / 2)];
            s0 += __uint_as_float(v << 16);
            s1 += __uint_as_float(v & 0xFFFF0000u);
        }
        float2 o = {s0, s1};
        *reinterpret_cast<float2*>(part + (size_t)s * ESPACE + 2 * e2) = o;
    } else {                                       // pl element (wave-uniform branch)
        int b = e2 - DD * BTOT / 2;                // 0..1023
        const float* p = pl + (size_t)c0 * BTOT + b;
        float v0 = 0.f;
        for (int i = 0; i < cper; ++i) v0 += p[(size_t)i * BTOT];
        part[(size_t)s * ESPACE + DD * BTOT + b] = v0;
    }
}

// ---------------- combine stage B: sum 8 slices + divide ----------------
__global__ __launch_bounds__(256)
void combineB(const float* __restrict__ part, float* __restrict__ out)
{
    int t = blockIdx.x * 256 + threadIdx.x;        // < 65536
    int d = t >> 10, b = t & 1023;
    float v = 0.f, lssum = 0.f;
#pragma unroll
    for (int s = 0; s < NSLICE; ++s) {
        v     += part[(size_t)s * ESPACE + t];
        lssum += part[(size_t)s * ESPACE + DD * BTOT + b];
    }
    out[(size_t)b * DD + d] = v / lssum;
}

extern "C" void kernel_launch(void* const* d_in, const int* in_sizes, int n_in,
                              void* d_out, int out_size, void* d_ws, size_t ws_size,
                              hipStream_t stream)
{
    const float* q    = (const float*)d_in[0];
    const float* ctx  = (const float*)d_in[1];
    const float* K    = (const float*)d_in[2];
    const float* V    = (const float*)d_in[3];
    const float* CT   = (const float*)d_in[4];
    const float* TS   = (const float*)d_in[5];
    const int*   mask = (const int*)d_in[6];

    char* wsb = (char*)d_ws;
    u16* Qc = (u16*)(wsb);                                // 1024*96*2   = 196608
    u16* KC = (u16*)(wsb + 196608);                       // 65536*96*2  = 12582912
    u16* Vt = (u16*)(wsb + 196608 + 12582912);            // 64*65536*2  = 8388608
    size_t fixed = 196608 + 12582912 + 8388608;           // 21168128

    int*   MaPtr      = (int*)(wsb + fixed);
    int*   blockCount = (int*)(wsb + fixed + 4096);
    int*   blockOff   = (int*)(wsb + fixed + 8192);
    int*   idxc       = (int*)(wsb + fixed + 12288);      // 65536*4
    float* biasc      = (float*)(wsb + fixed + 12288 + 262144);
    size_t scratch_end = fixed + 12288 + 524288;          // 21704704

    // chunk = pl (f32 1024) + pacc (bf16 65536)
    size_t chunk = (size_t)BTOT * 4 + (size_t)DD * BTOT * 2;     // 135168
    size_t partB = (size_t)NSLICE * ESPACE * sizeof(float);      // 2129920
    int SPLIT = (int)((ws_size - scratch_end - partB) / chunk);
    if (SPLIT > 128) SPLIT = 128;                          // NB=512 = 2 blocks/CU
    SPLIT &= ~7;
    if (SPLIT < 8) SPLIT = 8;

    float* pl    = (float*)(wsb + scratch_end);            // [SPLIT][1024] f32
    u16*   paccb = (u16*)(pl + (size_t)SPLIT * BTOT);      // [SPLIT][64][1024] bf16
    float* part  = (float*)(paccb + (size_t)SPLIT * DD * BTOT);  // [8][66560] f32

    int cper = SPLIT / NSLICE;

    k_count  <<<MTOT / 256, 256, 0, stream>>>(mask, blockCount);
    k_scan   <<<1, 256, 0, stream>>>(blockCount, blockOff, MaPtr);
    k_scatter<<<MTOT / 256, 256, 0, stream>>>(mask, TS, blockOff, idxc, biasc);

    prep_all<<<NROWBLK + NVTBLK, 256, 0, stream>>>(q, ctx, K, CT, V, MaPtr, idxc, biasc,
                                                   Qc, KC, Vt);

    int NB = 4 * SPLIT;                                    // 4 row-tiles of 256 rows
    epmem_mfma<<<NB, 512, 0, stream>>>(Qc, KC, Vt, MaPtr, pl, paccb, SPLIT, NB);

    // grid-x: 32768 pacc pairs + 1024 pl elems = 33792 threads = 132 blocks
    dim3 gA((DD * BTOT / 2 + BTOT + 255) / 256, NSLICE);
    combineA<<<gA, 256, 0, stream>>>(pl, (const u32*)paccb, part, cper);
    combineB<<<(DD * BTOT) / 256, 256, 0, stream>>>(part, (float*)d_out);
}

// Round 19
// 52.686 us; speedup vs baseline: 3.1070x; 1.0330x over previous
//
#include <hip/hip_runtime.h>

typedef float f32x4 __attribute__((ext_vector_type(4)));
typedef __bf16 bf16x8 __attribute__((ext_vector_type(8)));
typedef unsigned int u32;
typedef unsigned short u16;

#define MTOT 65536
#define BTOT 1024
#define DD 64
#define LOG2E 1.44269504088896340736f
#define MFMA __builtin_amdgcn_mfma_f32_16x16x32_bf16

#define NKCBLK (MTOT * 24 / 256)             // 6144 (KC row-gen blocks)
#define NVTBLK (MTOT / 64)                   // 1024
#define NQCBLK (BTOT * 24 / 256)             // 96  (Qc gen blocks, folded into k_count)
#define ESPACE (DD * BTOT + BTOT)            // 66560
#define NSLICE 8

__device__ __forceinline__ u16 f2bf(float f) { return __builtin_bit_cast(u16, (__bf16)f); }
__device__ __forceinline__ u32 pk2(float a, float b) {
    return (u32)f2bf(a) | ((u32)f2bf(b) << 16);
}
__device__ __forceinline__ bf16x8 ldg8(const u16* p) { return *reinterpret_cast<const bf16x8*>(p); }
__device__ __forceinline__ float fexp2(float x) {
#if __has_builtin(__builtin_amdgcn_exp2f)
    return __builtin_amdgcn_exp2f(x);
#else
    return exp2f(x);
#endif
}
__device__ __forceinline__ void glds16(const void* g, void* l) {
    __builtin_amdgcn_global_load_lds((const __attribute__((address_space(1))) u32*)g,
                                     (__attribute__((address_space(3))) u32*)l, 16, 0, 0);
}

// ---------------- k_count + Qc gen (independent work, one launch) ----------------
__global__ __launch_bounds__(256)
void k_count_qc(const int* __restrict__ mask,
                const float* __restrict__ q, const float* __restrict__ ctx,
                int* __restrict__ blockCount, u16* __restrict__ Qc)
{
    const int bid = blockIdx.x, t = threadIdx.x;
    if (bid < 256) {
        int m = bid * 256 + t;
        int active = mask[m] != 0;
        unsigned long long bal = __ballot(active);
        __shared__ int wc[4];
        if ((t & 63) == 0) wc[t >> 6] = __popcll(bal);
        __syncthreads();
        if (t == 0) blockCount[bid] = wc[0] + wc[1] + wc[2] + wc[3];
        return;
    }
    // Qc rows: 1024 * 24 quads
    int gid = (bid - 256) * 256 + t;
    int row = gid / 24, qd = gid - row * 24;
    float4 v = {0.f, 0.f, 0.f, 0.f};
    if (qd < 16) {
        v = *reinterpret_cast<const float4*>(q + (size_t)row * 64 + qd * 4);
        v.x *= LOG2E; v.y *= LOG2E; v.z *= LOG2E; v.w *= LOG2E;
    } else if (qd < 20) {
        v = *reinterpret_cast<const float4*>(ctx + (size_t)row * 16 + (qd - 16) * 4);
        const float s = 0.5f * LOG2E; v.x *= s; v.y *= s; v.z *= s; v.w *= s;
    } else if (qd == 20) {
        v.x = LOG2E;
    }
    ushort4 o = { f2bf(v.x), f2bf(v.y), f2bf(v.z), f2bf(v.w) };
    *reinterpret_cast<ushort4*>(Qc + (size_t)row * 96 + qd * 4) = o;
}

// ---------------- k_scatter with in-block scan of blockCount (replaces k_scan) ----------------
__global__ __launch_bounds__(256)
void k_scatter(const int* __restrict__ mask, const float* __restrict__ TS,
               const int* __restrict__ blockCount,
               int* __restrict__ idxc, float* __restrict__ biasc, int* __restrict__ MaPtr)
{
    __shared__ int sdata[256];
    __shared__ int wc[4];
    const int t = threadIdx.x, bid = blockIdx.x;
    int c = blockCount[t];
    sdata[t] = c;
    __syncthreads();
#pragma unroll
    for (int off = 1; off < 256; off <<= 1) {
        int x = (t >= off) ? sdata[t - off] : 0;
        __syncthreads();
        sdata[t] += x;
        __syncthreads();
    }
    if (bid == 0 && t == 255) *MaPtr = sdata[255];
    int base = (bid > 0) ? sdata[bid - 1] : 0;       // exclusive prefix for this block

    int m = bid * 256 + t;
    int active = mask[m] != 0;
    unsigned long long bal = __ballot(active);
    int lane = t & 63, wid = t >> 6;
    if (lane == 0) wc[wid] = __popcll(bal);
    __syncthreads();
    for (int w = 0; w < wid; ++w) base += wc[w];
    int rank = __popcll(bal & ((1ull << lane) - 1ull));
    if (active) {
        int dst = base + rank;
        idxc[dst]  = m;
        biasc[dst] = 0.3f * __expf(-0.1f * (1000.0f - TS[m]));
    }
}

// ---------------- gather-precompute: compacted KC rows + compacted interleaved Vt ----------------
__global__ __launch_bounds__(256)
void prep_all(const float* __restrict__ K, const float* __restrict__ CT,
              const float* __restrict__ V,
              const int* __restrict__ MaPtr, const int* __restrict__ idxc,
              const float* __restrict__ biasc,
              u16* __restrict__ KC, u16* __restrict__ Vt)
{
    __shared__ u16 L[64][68];
    const int blk = blockIdx.x, t = threadIdx.x;
    const int Ma = *MaPtr;
    const int Mpad = (Ma + 63) & ~63;

    if (blk < NKCBLK) {
        int gid = blk * 256 + t;                   // MTOT*24 total, exact
        float4 v = {0.f, 0.f, 0.f, 0.f};
        u16* dst;
        if (gid < MTOT * 16) {                     // feature cols 0..63
            int row = gid >> 4, qd = gid & 15;
            if (row >= Ma) return;                 // pad-row features: never matter
            v = *reinterpret_cast<const float4*>(K + (size_t)idxc[row] * 64 + qd * 4);
            dst = KC + (size_t)row * 96 + qd * 4;
        } else if (gid < MTOT * 20) {              // context cols 64..79
            int i = gid - MTOT * 16;
            int row = i >> 2, qd = i & 3;
            if (row >= Ma) return;
            v = *reinterpret_cast<const float4*>(CT + (size_t)idxc[row] * 16 + qd * 4);
            dst = KC + (size_t)row * 96 + 64 + qd * 4;
        } else {                                   // bias col 80 + pad 81..95
            int i = gid - MTOT * 20;
            int row = i >> 2, qd = i & 3;
            if (row >= Mpad) return;               // never read
            if (qd == 0) v.x = (row < Ma) ? biasc[row] : -1000.0f;   // pad rows -> exp2 == 0
            dst = KC + (size_t)row * 96 + 80 + qd * 4;
        }
        ushort4 o = { f2bf(v.x), f2bf(v.y), f2bf(v.z), f2bf(v.w) };
        *reinterpret_cast<ushort4*>(dst) = o;
        return;
    }

    // ---- Vt part: gather + interleaved transpose; blocks >= Mpad never read -> skip ----
    const int m0 = (blk - NKCBLK) * 64;
    if (m0 >= Mpad) return;
#pragma unroll
    for (int p = 0; p < 4; ++p) {
        int fi = t + p * 256;              // float4 index 0..1023
        int mi = fi >> 4, di = (fi & 15) << 2;
        int r = m0 + mi;
        float4 v = {0.f, 0.f, 0.f, 0.f};   // pad cols zero-filled (P=0 path, avoid NaN)
        if (r < Ma)
            v = *reinterpret_cast<const float4*>(V + (size_t)idxc[r] * 64 + di);
        ushort4 o = { f2bf(v.x), f2bf(v.y), f2bf(v.z), f2bf(v.w) };
        *reinterpret_cast<ushort4*>(&L[mi][di]) = o;
    }
    __syncthreads();
    const int d = t >> 2, seg = t & 3;
    u32 pk[8];
#pragma unroll
    for (int pr = 0; pr < 8; ++pr) {
        int c0 = seg * 16 + pr * 2;
        int g32 = c0 >> 5;
        int i0 = c0 & 31, i1 = (c0 + 1) & 31;
        int mp0 = g32 * 32 + (i0 >> 1) + (i0 & 1) * 16;   // interleave
        int mp1 = g32 * 32 + (i1 >> 1) + (i1 & 1) * 16;
        pk[pr] = (u32)L[mp0][d] | ((u32)L[mp1][d] << 16);
    }
    uint4 A = {pk[0], pk[1], pk[2], pk[3]}, B4 = {pk[4], pk[5], pk[6], pk[7]};
    u16* dst = Vt + (size_t)d * MTOT + m0 + seg * 16;
    *reinterpret_cast<uint4*>(dst)     = A;
    *reinterpret_cast<uint4*>(dst + 8) = B4;
}

// ---------------- main: compacted m-range, 8 waves/block, bf16 pacc (R18-proven) ----------------
__global__ __launch_bounds__(512, 4)
void epmem_mfma(const u16* __restrict__ Qc, const u16* __restrict__ KCg,
                const u16* __restrict__ Vtg, const int* __restrict__ MaPtr,
                float* __restrict__ pl, u16* __restrict__ paccb,
                int SPLIT, int NB)
{
    __shared__ __align__(16) u16 KCs[2][64 * 96];    // 24 KB
    __shared__ __align__(16) u16 Vts[2][64 * 64];    // 16 KB
    __shared__ __align__(16) u16 Pb[8][32][40];      // 20 KB

    const int tid = threadIdx.x;
    const int w = tid >> 6, lane = tid & 63;
    const int l15 = lane & 15, g = lane >> 4;

    const int bid = blockIdx.x;
    const int o = (bid & 7) * (NB >> 3) + (bid >> 3);     // XCD-bijective (NB % 8 == 0)
    const int rt = o & 3, ch = o >> 2;                    // 4 row-tiles of 256
    const int rbase = rt * 256 + w * 32;                  // wave owns 32 b-rows

    const u16* qp = Qc + (size_t)(rbase + l15) * 96 + g * 8;
    bf16x8 qf[2][3];
#pragma unroll
    for (int sb = 0; sb < 2; ++sb)
#pragma unroll
        for (int c = 0; c < 3; ++c)
            qf[sb][c] = ldg8(qp + sb * 16 * 96 + c * 32);

    const int Ma = *MaPtr;
    const int Mpad = (Ma + 63) & ~63;
    const int mper = ((Mpad + SPLIT - 1) / SPLIT + 63) & ~63;
    const int m0 = ch * mper;
    const int m1 = (m0 + mper < Mpad) ? (m0 + mper) : Mpad;
    const int ntiles = (m1 > m0) ? ((m1 - m0) >> 6) : 0;

    int kgo[3], vgo[2];
    if (w < 4) {
#pragma unroll
        for (int i = 0; i < 3; ++i) {
            int ol = w * 3072 + i * 1024 + lane * 16;
            int row = ol / 192;
            int c = (ol - row * 192) >> 4;                   // 0..11
            int u = (c < 8) ? (c ^ (row & 7)) : (8 + ((c & 3) ^ (row & 3)));
            kgo[i] = row * 192 + u * 16;
        }
#pragma unroll
        for (int i = 0; i < 2; ++i) {
            int ol = w * 2048 + i * 1024 + lane * 16;
            int row = ol >> 7, c = (ol >> 4) & 7;
            int u = c ^ (row & 7);
            vgo[i] = row * (MTOT * 2) + u * 16;
        }
    }

    const u32 ow = (l15 == 0) ? 0x3F803F80u : 0u;
    const uint4 ou = {ow, ow, ow, ow};
    const bf16x8 onesf = __builtin_bit_cast(bf16x8, ou);

    f32x4 acc[2][4];
    f32x4 accl[2];
#pragma unroll
    for (int sb = 0; sb < 2; ++sb) {
        accl[sb] = (f32x4){0, 0, 0, 0};
#pragma unroll
        for (int d4 = 0; d4 < 4; ++d4) acc[sb][d4] = (f32x4){0, 0, 0, 0};
    }

    if (ntiles > 0 && w < 4) {
        const char* kb = (const char*)KCg + (size_t)m0 * 192;
        const char* vb = (const char*)Vtg + (size_t)m0 * 2;
#pragma unroll
        for (int i = 0; i < 3; ++i) glds16(kb + kgo[i], (char*)KCs[0] + w * 3072 + i * 1024);
#pragma unroll
        for (int i = 0; i < 2; ++i) glds16(vb + vgo[i], (char*)Vts[0] + w * 2048 + i * 1024);
    }
    __syncthreads();

    char* pbw = (char*)Pb[w];
    const int xr = l15 & 7;
    const int x3 = l15 & 3;

    int cur = 0;
    for (int t = 0; t < ntiles; ++t) {
        if (t + 1 < ntiles && w < 4) {
            int mt = m0 + ((t + 1) << 6);
            const char* kb = (const char*)KCg + (size_t)mt * 192;
            const char* vb = (const char*)Vtg + (size_t)mt * 2;
            int nb = cur ^ 1;
#pragma unroll
            for (int i = 0; i < 3; ++i) glds16(kb + kgo[i], (char*)KCs[nb] + w * 3072 + i * 1024);
#pragma unroll
            for (int i = 0; i < 2; ++i) glds16(vb + vgo[i], (char*)Vts[nb] + w * 2048 + i * 1024);
        }
        const char* kcb = (const char*)KCs[cur];
        const char* vtb = (const char*)Vts[cur];

#pragma unroll
        for (int j = 0; j < 2; ++j) {               // two 32-m steps per 64-m tile
            bf16x8 kf[2][3];
#pragma unroll
            for (int s = 0; s < 2; ++s) {
                int row = j * 32 + s * 16 + l15;
                kf[s][0] = *reinterpret_cast<const bf16x8*>(kcb + row * 192 + (((0 + g) ^ xr) << 4));
                kf[s][1] = *reinterpret_cast<const bf16x8*>(kcb + row * 192 + (((4 + g) ^ xr) << 4));
                kf[s][2] = *reinterpret_cast<const bf16x8*>(kcb + row * 192 + ((8 + (g ^ x3)) << 4));
            }
            bf16x8 vf[4];
#pragma unroll
            for (int d4 = 0; d4 < 4; ++d4) {
                int row = d4 * 16 + l15;
                vf[d4] = *reinterpret_cast<const bf16x8*>(vtb + row * 128 + (((j * 4 + g) ^ xr) << 4));
            }

            f32x4 S00 = {0,0,0,0}, S01 = {0,0,0,0}, S10 = {0,0,0,0}, S11 = {0,0,0,0};
            S00 = MFMA(qf[0][0], kf[0][0], S00,0,0,0); S00 = MFMA(qf[0][1], kf[0][1], S00,0,0,0); S00 = MFMA(qf[0][2], kf[0][2], S00,0,0,0);
            S01 = MFMA(qf[0][0], kf[1][0], S01,0,0,0); S01 = MFMA(qf[0][1], kf[1][1], S01,0,0,0); S01 = MFMA(qf[0][2], kf[1][2], S01,0,0,0);
            S10 = MFMA(qf[1][0], kf[0][0], S10,0,0,0); S10 = MFMA(qf[1][1], kf[0][1], S10,0,0,0); S10 = MFMA(qf[1][2], kf[0][2], S10,0,0,0);
            S11 = MFMA(qf[1][0], kf[1][0], S11,0,0,0); S11 = MFMA(qf[1][1], kf[1][1], S11,0,0,0); S11 = MFMA(qf[1][2], kf[1][2], S11,0,0,0);

#pragma unroll
            for (int r = 0; r < 4; ++r) {
                float p00 = fexp2(S00[r]), p01 = fexp2(S01[r]);
                float p10 = fexp2(S10[r]), p11 = fexp2(S11[r]);
                int row0 = g * 4 + r, row1 = 16 + g * 4 + r;
                int cw = (((l15 >> 2) ^ r) << 4) | ((l15 & 3) << 2);
                *(u32*)(pbw + row0 * 80 + cw) = pk2(p00, p01);   // pair (m'=l15, 16+l15)
                *(u32*)(pbw + row1 * 80 + cw) = pk2(p10, p11);
            }
            bf16x8 pa0 = *reinterpret_cast<const bf16x8*>(pbw + l15 * 80        + ((g ^ x3) << 4));
            bf16x8 pa1 = *reinterpret_cast<const bf16x8*>(pbw + (16 + l15) * 80 + ((g ^ x3) << 4));

            acc[0][0] = MFMA(pa0, vf[0], acc[0][0],0,0,0); acc[0][1] = MFMA(pa0, vf[1], acc[0][1],0,0,0);
            acc[0][2] = MFMA(pa0, vf[2], acc[0][2],0,0,0); acc[0][3] = MFMA(pa0, vf[3], acc[0][3],0,0,0);
            acc[1][0] = MFMA(pa1, vf[0], acc[1][0],0,0,0); acc[1][1] = MFMA(pa1, vf[1], acc[1][1],0,0,0);
            acc[1][2] = MFMA(pa1, vf[2], acc[1][2],0,0,0); acc[1][3] = MFMA(pa1, vf[3], acc[1][3],0,0,0);
            accl[0] = MFMA(pa0, onesf, accl[0],0,0,0);     // lsum of quantized P
            accl[1] = MFMA(pa1, onesf, accl[1],0,0,0);
        }
        __syncthreads();
        cur ^= 1;
    }

    // pl[ch][b] (f32): lsum in col 0 of accl (lanes l15==0)
    if (l15 == 0) {
#pragma unroll
        for (int sb = 0; sb < 2; ++sb)
            *reinterpret_cast<f32x4*>(pl + (size_t)ch * BTOT + rbase + sb * 16 + g * 4) = accl[sb];
    }

    // paccb[ch][d][b] (bf16, packed pairs along b)
#pragma unroll
    for (int sb = 0; sb < 2; ++sb)
#pragma unroll
        for (int d4 = 0; d4 < 4; ++d4) {
            uint2 wv;
            wv.x = pk2(acc[sb][d4][0], acc[sb][d4][1]);
            wv.y = pk2(acc[sb][d4][2], acc[sb][d4][3]);
            *reinterpret_cast<uint2*>(paccb + ((size_t)ch * DD + d4 * 16 + l15) * BTOT
                                      + rbase + sb * 16 + g * 4) = wv;
        }
}

// ---------------- combine stage A: slice-reduce chunks (bf16 pacc, f32 pl) ----------------
__global__ __launch_bounds__(256)
void combineA(const float* __restrict__ pl, const u32* __restrict__ paccb,
              float* __restrict__ part, int cper)
{
    int e2 = blockIdx.x * 256 + threadIdx.x;       // pair index < 32768, then pl 1024
    int s = blockIdx.y;
    int c0 = s * cper;
    if (e2 < (DD * BTOT / 2)) {                    // pacc pair (2 consecutive b)
        const u32* p = paccb + (size_t)c0 * (DD * BTOT / 2) + e2;
        float s0 = 0.f, s1 = 0.f;
        for (int i = 0; i < cper; ++i) {
            u32 v = p[(size_t)i * (DD * BTOT / 2)];
            s0 += __uint_as_float(v << 16);
            s1 += __uint_as_float(v & 0xFFFF0000u);
        }
        float2 o = {s0, s1};
        *reinterpret_cast<float2*>(part + (size_t)s * ESPACE + 2 * e2) = o;
    } else {                                       // pl element (wave-uniform branch)
        int b = e2 - DD * BTOT / 2;                // 0..1023
        const float* p = pl + (size_t)c0 * BTOT + b;
        float v0 = 0.f;
        for (int i = 0; i < cper; ++i) v0 += p[(size_t)i * BTOT];
        part[(size_t)s * ESPACE + DD * BTOT + b] = v0;
    }
}

// ---------------- combine stage B: sum 8 slices + divide ----------------
__global__ __launch_bounds__(256)
void combineB(const float* __restrict__ part, float* __restrict__ out)
{
    int t = blockIdx.x * 256 + threadIdx.x;        // < 65536
    int d = t >> 10, b = t & 1023;
    float v = 0.f, lssum = 0.f;
#pragma unroll
    for (int s = 0; s < NSLICE; ++s) {
        v     += part[(size_t)s * ESPACE + t];
        lssum += part[(size_t)s * ESPACE + DD * BTOT + b];
    }
    out[(size_t)b * DD + d] = v / lssum;
}

extern "C" void kernel_launch(void* const* d_in, const int* in_sizes, int n_in,
                              void* d_out, int out_size, void* d_ws, size_t ws_size,
                              hipStream_t stream)
{
    const float* q    = (const float*)d_in[0];
    const float* ctx  = (const float*)d_in[1];
    const float* K    = (const float*)d_in[2];
    const float* V    = (const float*)d_in[3];
    const float* CT   = (const float*)d_in[4];
    const float* TS   = (const float*)d_in[5];
    const int*   mask = (const int*)d_in[6];

    char* wsb = (char*)d_ws;
    u16* Qc = (u16*)(wsb);                                // 1024*96*2   = 196608
    u16* KC = (u16*)(wsb + 196608);                       // 65536*96*2  = 12582912
    u16* Vt = (u16*)(wsb + 196608 + 12582912);            // 64*65536*2  = 8388608
    size_t fixed = 196608 + 12582912 + 8388608;           // 21168128

    int*   MaPtr      = (int*)(wsb + fixed);
    int*   blockCount = (int*)(wsb + fixed + 4096);
    int*   idxc       = (int*)(wsb + fixed + 12288);      // 65536*4
    float* biasc      = (float*)(wsb + fixed + 12288 + 262144);
    size_t scratch_end = fixed + 12288 + 524288;          // 21704704

    // chunk = pl (f32 1024) + pacc (bf16 65536)
    size_t chunk = (size_t)BTOT * 4 + (size_t)DD * BTOT * 2;     // 135168
    size_t partB = (size_t)NSLICE * ESPACE * sizeof(float);      // 2129920
    int SPLIT = (int)((ws_size - scratch_end - partB) / chunk);
    if (SPLIT > 128) SPLIT = 128;                          // NB=512 = 2 blocks/CU
    SPLIT &= ~7;
    if (SPLIT < 8) SPLIT = 8;

    float* pl    = (float*)(wsb + scratch_end);            // [SPLIT][1024] f32
    u16*   paccb = (u16*)(pl + (size_t)SPLIT * BTOT);      // [SPLIT][64][1024] bf16
    float* part  = (float*)(paccb + (size_t)SPLIT * DD * BTOT);  // [8][66560] f32

    int cper = SPLIT / NSLICE;

    k_count_qc<<<256 + NQCBLK, 256, 0, stream>>>(mask, q, ctx, blockCount, Qc);
    k_scatter <<<MTOT / 256, 256, 0, stream>>>(mask, TS, blockCount, idxc, biasc, MaPtr);

    prep_all<<<NKCBLK + NVTBLK, 256, 0, stream>>>(K, CT, V, MaPtr, idxc, biasc, KC, Vt);

    int NB = 4 * SPLIT;                                    // 4 row-tiles of 256 rows
    epmem_mfma<<<NB, 512, 0, stream>>>(Qc, KC, Vt, MaPtr, pl, paccb, SPLIT, NB);

    dim3 gA((DD * BTOT / 2 + BTOT + 255) / 256, NSLICE);
    combineA<<<gA, 256, 0, stream>>>(pl, (const u32*)paccb, part, cper);
    combineB<<<(DD * BTOT) / 256, 256, 0, stream>>>(part, (float*)d_out);
}